// Round 1
// baseline (170.276 us; speedup 1.0000x reference)
//
#include <hip/hip_runtime.h>
#include <stdint.h>

#define B_ 2048
#define T_ 256
#define V_ 128
#define E_ 128
#define H_ 64
#define G4_ 256  // 4*H
#define POS_W 20.0f
#define MB_ 8            // batch rows per block: row q at M-row 4q (C-reg 0), row q+4 at M-row 4q+1 (C-reg 1)
#define NBLK_ (B_ / MB_) // 256 blocks = 1 block/CU: no co-resident block to phase-lock with
typedef _Float16 half1;
typedef __attribute__((ext_vector_type(8))) _Float16 f16x8;
typedef __attribute__((ext_vector_type(4))) float f32x4;

#if __has_builtin(__builtin_amdgcn_exp2f)
#define EXP2F(x) __builtin_amdgcn_exp2f(x)
#else
#define EXP2F(x) exp2f(x)
#endif

#if __has_builtin(__builtin_amdgcn_rcpf)
#define RCPF(x) __builtin_amdgcn_rcpf(x)
#else
#define RCPF(x) (1.0f / (x))
#endif

__device__ __forceinline__ float sigm(float x) {
    return RCPF(1.0f + EXP2F(-1.44269504f * x));
}
__device__ __forceinline__ float tanhr(float x) {
    // tanh(x) = 1 - 2/(e^(2x)+1); exp2 over/underflow saturates correctly
    float t = EXP2F(2.88539008f * x);
    return 1.0f - 2.0f * RCPF(t + 1.0f);
}

// Barrier draining ONLY lgkmcnt: keeps L2 proj-prefetches (vmcnt) in flight
// across the step boundary. Safe: h-exchange is double-buffered; in-flight
// global loads only write registers.
__device__ __forceinline__ void lds_barrier() {
    asm volatile("s_waitcnt lgkmcnt(0)\n\ts_barrier" ::: "memory");
}

// ---------------------------------------------------------------------------
// k_prep: projC[v][u][g] = dot(emb[v], W_ih[g*64+u]) + b_ih + b_hh   (f32)
// Layout [v][unit][gate]: LSTM kernel gathers one float4 per (v,unit).
// Block 0 / tid 0 zeroes the loss accumulator.
// ---------------------------------------------------------------------------
__global__ void k_prep(const float* __restrict__ emb, const float* __restrict__ Wih,
                       const float* __restrict__ bih, const float* __restrict__ bhh,
                       float* __restrict__ projC, float* __restrict__ loss_slot) {
    int tid = threadIdx.x;  // 0..255; u = tid>>2, g = tid&3
    int v = blockIdx.x;
    if (v == 0 && tid == 0) *loss_slot = 0.0f;
    int u = tid >> 2, g = tid & 3;
    int row = g * 64 + u;
    const float4* e4 = (const float4*)(emb + v * E_);
    const float4* w4 = (const float4*)(Wih + row * E_);
    float acc = bih[row] + bhh[row];
#pragma unroll
    for (int i = 0; i < E_ / 4; ++i) {
        float4 a = e4[i];
        float4 b = w4[i];
        acc += a.x * b.x + a.y * b.y + a.z * b.z + a.w * b.w;
    }
    projC[v * G4_ + tid] = acc;  // coalesced
}

// ---------------------------------------------------------------------------
// k_lstm: MFMA recurrence, gate-permuted B, 2 cells per thread.
// R9: counters showed per-SIMD VALU issue ~473 cyc/step but step = 927 cyc:
// the two co-resident blocks phase-locked and serialized (s_sleep de-phase
// didn't hold). Fix: fold the second block INTO the wave — 8 rows/block,
// 256 blocks = 1 block/CU. Rows q (M-row 4q, C-reg 0) and q+4 (M-row 4q+1,
// C-reg 1) share the same 8 MFMAs; the 2 independent cells per lane give the
// compiler ILP to fill the ds_read/MFMA latency that the second block used
// to (unreliably) fill. MFMAs and barriers per useful output halve.
// ---------------------------------------------------------------------------
__launch_bounds__(256, 1)
__global__ void k_lstm(const int* __restrict__ x, const float* __restrict__ Whh,
                       const float* __restrict__ projC, const float* __restrict__ Wfc,
                       const float* __restrict__ bfc, const float* __restrict__ targets,
                       float* __restrict__ logits, float* __restrict__ loss_slot) {
    int b0 = blockIdx.x * MB_;
    int t = threadIdx.x;         // 0..255
    int w = t >> 6, l = t & 63;  // wave, lane
    int q = l >> 4, cc = l & 15;
    int u = 16 * w + cc;  // unit owned by this lane (all 4 gates), rows q and q+4

    __shared__ __align__(16) half1 hf[2][1024];  // A-layout h, double-buffered
    __shared__ int xT[T_][MB_];                  // transposed token indices
    __shared__ float hfin[MB_][68];              // final h (padded)
    __shared__ float zred[MB_];

    // stage xT (coalesced: fixed i, consecutive t)
#pragma unroll
    for (int i = 0; i < MB_; ++i) xT[t][i] = x[(b0 + i) * T_ + t];
    ((float*)hf)[t] = 0.0f;
    ((float*)hf)[t + 256] = 0.0f;
    ((float*)hf)[t + 512] = 0.0f;
    ((float*)hf)[t + 768] = 0.0f;
    __syncthreads();

    // B-fragments inline from W_hh (f32, L2): N-tile jj, K-chunk c.
    // frag elem j: B[k=c*32+q*8+j][col cc] = Whh[jj*64+16w+cc][k]  (R5-R8 verified)
    f16x8 bf[4][2];
#pragma unroll
    for (int jj = 0; jj < 4; ++jj) {
#pragma unroll
        for (int c = 0; c < 2; ++c) {
            int row = jj * 64 + 16 * w + cc;
            int kb = c * 32 + q * 8;
            float4 w0 = *(const float4*)(Whh + row * H_ + kb);
            float4 w1 = *(const float4*)(Whh + row * H_ + kb + 4);
            f16x8 tmp;
            tmp[0] = (half1)w0.x; tmp[1] = (half1)w0.y;
            tmp[2] = (half1)w0.z; tmp[3] = (half1)w0.w;
            tmp[4] = (half1)w1.x; tmp[5] = (half1)w1.y;
            tmp[6] = (half1)w1.z; tmp[7] = (half1)w1.w;
            bf[jj][c] = tmp;
        }
    }

    // h-write slot for (unit u, M-row 4q):
    // f16 idx = (u>>5)*512 + ((u>>3)&3)*128 + (4q)*8 + (u&7); row 4q+1 is +8
    int hbase = (u >> 5) * 512 + ((u >> 3) & 3) * 128 + (4 * q) * 8 + (u & 7);

    float cA = 0.0f, hA = 0.0f;  // batch row q
    float cB = 0.0f, hB = 0.0f;  // batch row q+4

    // prefetch proj for steps 0 and 1 (depth 2); same-q lanes broadcast-read xT
    f32x4 ppA = *(const f32x4*)(projC + xT[0][q] * G4_ + u * 4);
    f32x4 ppB = *(const f32x4*)(projC + xT[0][q + 4] * G4_ + u * 4);
    f32x4 pnA = *(const f32x4*)(projC + xT[1][q] * G4_ + u * 4);
    f32x4 pnB = *(const f32x4*)(projC + xT[1][q + 4] * G4_ + u * 4);

    int p = 0;
#pragma unroll 2
    for (int step = 0; step < T_; ++step) {
        // depth-2 prefetch (consumed at step+2; wraps harmlessly at tail)
        int t2 = (step + 2) & (T_ - 1);
        f32x4 p2A = *(const f32x4*)(projC + xT[t2][q] * G4_ + u * 4);
        f32x4 p2B = *(const f32x4*)(projC + xT[t2][q + 4] * G4_ + u * 4);

        // A-fragments of h_t (conflict-free lane-contiguous b128)
        const f16x8 a0 = *(const f16x8*)(hf[p] + l * 8);
        const f16x8 a1 = *(const f16x8*)(hf[p] + 512 + l * 8);

        // gates for (rows q & q+4, unit u): C-regs [0] and [1] live.
        // Chained accumulate: d = a1*bf1 + (a0*bf0 + 0) — no v_adds needed.
        f32x4 z4 = {0.0f, 0.0f, 0.0f, 0.0f};
        float gA[4], gB[4];
#pragma unroll
        for (int jj = 0; jj < 4; ++jj) {
            f32x4 d0 = __builtin_amdgcn_mfma_f32_16x16x32_f16(a0, bf[jj][0], z4, 0, 0, 0);
            f32x4 d = __builtin_amdgcn_mfma_f32_16x16x32_f16(a1, bf[jj][1], d0, 0, 0, 0);
            gA[jj] = d[0];
            gB[jj] = d[1];
        }

        // cell updates; pp was loaded 2 steps ago (never waited).
        // Two independent chains — compiler interleaves for ILP.
        float iA = sigm(gA[0] + ppA.x);
        float fA = sigm(gA[1] + ppA.y);
        float ggA = tanhr(gA[2] + ppA.z);
        float oA = sigm(gA[3] + ppA.w);
        cA = fA * cA + iA * ggA;
        hA = oA * tanhr(cA);

        float iB = sigm(gB[0] + ppB.x);
        float fB = sigm(gB[1] + ppB.y);
        float ggB = tanhr(gB[2] + ppB.z);
        float oB = sigm(gB[3] + ppB.w);
        cB = fB * cB + iB * ggB;
        hB = oB * tanhr(cB);

        // publish h_{t+1} (A-layout, other buffer)
        hf[p ^ 1][hbase] = (half1)hA;
        hf[p ^ 1][hbase + 8] = (half1)hB;

        ppA = pnA; ppB = pnB;
        pnA = p2A; pnB = p2B;
        p ^= 1;
        lds_barrier();  // lgkmcnt-only: proj prefetches stay in flight
    }

    // epilogue: logits + fused loss
    hfin[q][u] = hA;
    hfin[q + 4][u] = hB;
    __syncthreads();
    int m4 = t >> 6, uu = t & 63;  // wave m4 reduces batch rows m4 and m4+4
    float wv = Wfc[uu];
    float pa = hfin[m4][uu] * wv;
    float pb = hfin[m4 + 4][uu] * wv;
#pragma unroll
    for (int off = 32; off > 0; off >>= 1) {
        pa += __shfl_down(pa, off, 64);
        pb += __shfl_down(pb, off, 64);
    }
    if (uu == 0) {
        float z = pa + bfc[0];
        logits[b0 + m4] = z;
        float tg = targets[b0 + m4];
        float e = EXP2F(-1.44269504f * fabsf(z));
        float lsp = fminf(z, 0.0f) - log1pf(e);
        float lsn = lsp - z;
        zred[m4] = -(POS_W * tg * lsp + (1.0f - tg) * lsn) * (1.0f / (float)B_);

        float z2 = pb + bfc[0];
        logits[b0 + m4 + 4] = z2;
        float tg2 = targets[b0 + m4 + 4];
        float e2 = EXP2F(-1.44269504f * fabsf(z2));
        float lsp2 = fminf(z2, 0.0f) - log1pf(e2);
        float lsn2 = lsp2 - z2;
        zred[m4 + 4] = -(POS_W * tg2 * lsp2 + (1.0f - tg2) * lsn2) * (1.0f / (float)B_);
    }
    __syncthreads();
    if (t == 0) {
        float s = 0.0f;
#pragma unroll
        for (int i = 0; i < MB_; ++i) s += zred[i];
        atomicAdd(loss_slot, s);
    }
}

// ---------------------------------------------------------------------------
extern "C" void kernel_launch(void* const* d_in, const int* in_sizes, int n_in,
                              void* d_out, int out_size, void* d_ws, size_t ws_size,
                              hipStream_t stream) {
    const int* x = (const int*)d_in[0];
    const float* targets = (const float*)d_in[1];
    const float* emb = (const float*)d_in[2];
    const float* Wih = (const float*)d_in[3];
    const float* Whh = (const float*)d_in[4];
    const float* bih = (const float*)d_in[5];
    const float* bhh = (const float*)d_in[6];
    const float* Wfc = (const float*)d_in[7];
    const float* bfc = (const float*)d_in[8];
    float* out = (float*)d_out;  // [0..2047] logits, [2048] loss

    float* projC = (float*)d_ws;  // 128*256*4 = 128 KiB

    k_prep<<<dim3(V_), dim3(256), 0, stream>>>(emb, Wih, bih, bhh, projC, out + B_);
    k_lstm<<<dim3(NBLK_), dim3(256), 0, stream>>>(x, Whh, projC, Wfc, bfc, targets, out,
                                                  out + B_);
}

// Round 4
// 158.235 us; speedup vs baseline: 1.0761x; 1.0761x over previous
//
#include <hip/hip_runtime.h>
#include <stdint.h>

#define B_ 2048
#define T_ 256
#define V_ 128
#define E_ 128
#define H_ 64
#define G4_ 256  // 4*H
#define POS_W 20.0f
#define MB_ 4            // batch rows per block: row j at M-row 4j (C-reg[0] of lane quad j)
#define NBLK_ (B_ / MB_) // 512 blocks = 2 blocks/CU = 2 waves/SIMD
typedef _Float16 half1;
typedef __attribute__((ext_vector_type(8))) _Float16 f16x8;
typedef __attribute__((ext_vector_type(4))) float f32x4;

#if __has_builtin(__builtin_amdgcn_exp2f)
#define EXP2F(x) __builtin_amdgcn_exp2f(x)
#else
#define EXP2F(x) exp2f(x)
#endif

#if __has_builtin(__builtin_amdgcn_rcpf)
#define RCPF(x) __builtin_amdgcn_rcpf(x)
#else
#define RCPF(x) (1.0f / (x))
#endif

__device__ __forceinline__ float sigm(float x) {
    return RCPF(1.0f + EXP2F(-1.44269504f * x));
}
__device__ __forceinline__ float tanhr(float x) {
    // tanh(x) = 1 - 2/(e^(2x)+1); exp2 over/underflow saturates correctly
    float t = EXP2F(2.88539008f * x);
    return 1.0f - 2.0f * RCPF(t + 1.0f);
}

// Barrier draining ONLY lgkmcnt: keeps L2 proj-prefetches (vmcnt) in flight
// across the step boundary. Safe: h-exchange is double-buffered; in-flight
// global loads only write registers.
__device__ __forceinline__ void lds_barrier() {
    asm volatile("s_waitcnt lgkmcnt(0)\n\ts_barrier" ::: "memory");
}

// ---------------------------------------------------------------------------
// k_prep: projC[v][u][g] = dot(emb[v], W_ih[g*64+u]) + b_ih + b_hh   (f32)
// Layout [v][unit][gate]: LSTM kernel gathers one float4 per (v,unit).
// Block 0 / tid 0 zeroes the loss accumulator.
// ---------------------------------------------------------------------------
__global__ void k_prep(const float* __restrict__ emb, const float* __restrict__ Wih,
                       const float* __restrict__ bih, const float* __restrict__ bhh,
                       float* __restrict__ projC, float* __restrict__ loss_slot) {
    int tid = threadIdx.x;  // 0..255; u = tid>>2, g = tid&3
    int v = blockIdx.x;
    if (v == 0 && tid == 0) *loss_slot = 0.0f;
    int u = tid >> 2, g = tid & 3;
    int row = g * 64 + u;
    const float4* e4 = (const float4*)(emb + v * E_);
    const float4* w4 = (const float4*)(Wih + row * E_);
    float acc = bih[row] + bhh[row];
#pragma unroll
    for (int i = 0; i < E_ / 4; ++i) {
        float4 a = e4[i];
        float4 b = w4[i];
        acc += a.x * b.x + a.y * b.y + a.z * b.z + a.w * b.w;
    }
    projC[v * G4_ + tid] = acc;  // coalesced
}

// ---------------------------------------------------------------------------
// k_lstm: MFMA recurrence, gate-permuted B, 1 cell per thread.
// R9/R10 model: time = 256 steps x L where L is the per-step serial chain
// (barrier -> ds_read h -> MFMA -> gate VALU -> ds_write h -> barrier).
// Occupancy does NOT matter (every chain must traverse 256xL); only L does.
// Chain-shortening levers under test (R12 = R10 minus setprio, de-risked
// after two container failures on the setprio variant):
//   - proj bias folded into MFMA C-operand (C[0] = pp[gate])
//   - independent (unchained) K-chunk MFMAs: d0[0]+d1[0]
//   - prefetch block AFTER MFMA issue (sits in MFMA shadow, off chain entry)
//   - xT token pre-read 1 step ahead into a register, as byte offset
// ---------------------------------------------------------------------------
__launch_bounds__(256, 2)
__global__ void k_lstm(const int* __restrict__ x, const float* __restrict__ Whh,
                       const float* __restrict__ projC, const float* __restrict__ Wfc,
                       const float* __restrict__ bfc, const float* __restrict__ targets,
                       float* __restrict__ logits, float* __restrict__ loss_slot) {
    int b0 = blockIdx.x * MB_;
    int t = threadIdx.x;         // 0..255
    int w = t >> 6, l = t & 63;  // wave, lane
    int q = l >> 4, cc = l & 15;
    int u = 16 * w + cc;  // unit owned by this lane (all 4 gates), batch row q

    __shared__ __align__(16) half1 hf[2][1024];  // A-layout h, double-buffered
    __shared__ int xT[T_][MB_];                  // token byte-offsets (tok<<10)
    __shared__ float hfin[MB_][68];              // final h (padded)
    __shared__ float zred[MB_];

    // stage xT (coalesced: fixed i, consecutive t); pre-scale to byte offset
#pragma unroll
    for (int i = 0; i < MB_; ++i) xT[t][i] = x[(b0 + i) * T_ + t] << 10;  // *G4_*4
    ((float*)hf)[t] = 0.0f;
    ((float*)hf)[t + 256] = 0.0f;
    ((float*)hf)[t + 512] = 0.0f;
    ((float*)hf)[t + 768] = 0.0f;
    __syncthreads();

    // B-fragments inline from W_hh (f32, L2): N-tile jj, K-chunk c.
    // frag elem j: B[k=c*32+q*8+j][col cc] = Whh[jj*64+16w+cc][k]  (R5-R8 verified)
    f16x8 bf[4][2];
#pragma unroll
    for (int jj = 0; jj < 4; ++jj) {
#pragma unroll
        for (int c = 0; c < 2; ++c) {
            int row = jj * 64 + 16 * w + cc;
            int kb = c * 32 + q * 8;
            float4 w0 = *(const float4*)(Whh + row * H_ + kb);
            float4 w1 = *(const float4*)(Whh + row * H_ + kb + 4);
            f16x8 tmp;
            tmp[0] = (half1)w0.x; tmp[1] = (half1)w0.y;
            tmp[2] = (half1)w0.z; tmp[3] = (half1)w0.w;
            tmp[4] = (half1)w1.x; tmp[5] = (half1)w1.y;
            tmp[6] = (half1)w1.z; tmp[7] = (half1)w1.w;
            bf[jj][c] = tmp;
        }
    }

    // h-write slot for (unit u, M-row 4q):
    // f16 idx = (u>>5)*512 + ((u>>3)&3)*128 + (4q)*8 + (u&7)
    int hbase = (u >> 5) * 512 + ((u >> 3) & 3) * 128 + (4 * q) * 8 + (u & 7);

    float cA = 0.0f, hA = 0.0f;
    const char* pcb = (const char*)projC;
    int uoff = u << 4;  // u*16 bytes

    // prefetch proj for steps 0 and 1 (depth 2); same-q lanes broadcast-read xT
    f32x4 ppA = *(const f32x4*)(pcb + xT[0][q] + uoff);
    f32x4 pnA = *(const f32x4*)(pcb + xT[1][q] + uoff);
    int xcA = xT[2][q];  // token byte-offset for step+2's proj load

    const f32x4 z4 = {0.0f, 0.0f, 0.0f, 0.0f};
    int p = 0;
#pragma unroll 2
    for (int step = 0; step < T_; ++step) {
        // ---- chain head: A-fragments of h_t (conflict-free lane-contiguous b128)
        const f16x8 a0 = *(const f16x8*)(hf[p] + l * 8);
        const f16x8 a1 = *(const f16x8*)(hf[p] + 512 + l * 8);

        // gates for (row q, unit u): only C-reg[0] live. pp folded into C of d0;
        // K-chunk MFMAs independent (unchained) -> single MFMA latency + 1 add.
        float gA[4];
#pragma unroll
        for (int jj = 0; jj < 4; ++jj) {
            f32x4 c4 = z4;
            c4[0] = ppA[jj];
            f32x4 d0 = __builtin_amdgcn_mfma_f32_16x16x32_f16(a0, bf[jj][0], c4, 0, 0, 0);
            f32x4 d1 = __builtin_amdgcn_mfma_f32_16x16x32_f16(a1, bf[jj][1], z4, 0, 0, 0);
            gA[jj] = d0[0] + d1[0];
        }

        // ---- off-chain: prefetch (issues while MFMAs are in flight)
        f32x4 p2A = *(const f32x4*)(pcb + xcA + uoff);           // proj for step+2
        int xnA = xT[(step + 3) & (T_ - 1)][q];                  // token for step+3

        // ---- chain tail: cell update (pp never waited)
        float iA = sigm(gA[0]);
        float fA = sigm(gA[1]);
        float ggA = tanhr(gA[2]);
        float oA = sigm(gA[3]);
        cA = fA * cA + iA * ggA;
        hA = oA * tanhr(cA);

        // publish h_{t+1} (A-layout, other buffer)
        hf[p ^ 1][hbase] = (half1)hA;

        ppA = pnA;
        pnA = p2A;
        xcA = xnA;
        p ^= 1;
        lds_barrier();  // lgkmcnt-only: proj prefetches stay in flight
    }

    // epilogue: logits + fused loss
    hfin[q][u] = hA;
    __syncthreads();
    int m4 = t >> 6, uu = t & 63;  // wave m4 reduces batch row m4
    float part = hfin[m4][uu] * Wfc[uu];
#pragma unroll
    for (int off = 32; off > 0; off >>= 1) part += __shfl_down(part, off, 64);
    if (uu == 0) {
        float z = part + bfc[0];
        logits[b0 + m4] = z;
        float tg = targets[b0 + m4];
        float e = EXP2F(-1.44269504f * fabsf(z));
        float lsp = fminf(z, 0.0f) - log1pf(e);
        float lsn = lsp - z;
        zred[m4] = -(POS_W * tg * lsp + (1.0f - tg) * lsn) * (1.0f / (float)B_);
    }
    __syncthreads();
    if (t == 0) {
        float s = 0.0f;
#pragma unroll
        for (int i = 0; i < MB_; ++i) s += zred[i];
        atomicAdd(loss_slot, s);
    }
}

// ---------------------------------------------------------------------------
extern "C" void kernel_launch(void* const* d_in, const int* in_sizes, int n_in,
                              void* d_out, int out_size, void* d_ws, size_t ws_size,
                              hipStream_t stream) {
    const int* x = (const int*)d_in[0];
    const float* targets = (const float*)d_in[1];
    const float* emb = (const float*)d_in[2];
    const float* Wih = (const float*)d_in[3];
    const float* Whh = (const float*)d_in[4];
    const float* bih = (const float*)d_in[5];
    const float* bhh = (const float*)d_in[6];
    const float* Wfc = (const float*)d_in[7];
    const float* bfc = (const float*)d_in[8];
    float* out = (float*)d_out;  // [0..2047] logits, [2048] loss

    float* projC = (float*)d_ws;  // 128*256*4 = 128 KiB

    k_prep<<<dim3(V_), dim3(256), 0, stream>>>(emb, Wih, bih, bhh, projC, out + B_);
    k_lstm<<<dim3(NBLK_), dim3(256), 0, stream>>>(x, Whh, projC, Wfc, bfc, targets, out,
                                                  out + B_);
}